// Round 1
// baseline (159.859 us; speedup 1.0000x reference)
//
#include <hip/hip_runtime.h>
#include <hip/hip_bf16.h>
#include <stdint.h>

// STAR-DNN: per-sample scene-selected 3-layer MLP.
// R1: LDS-histogram compaction. R2: global_load_lds DMA. R4 (failed): grid
// barrier ~140us on 8 XCDs. R6 (failed): 135-blk fusion starved CUs.
// R8 (failed): gemm0 at 1 blk/CU latency-bound. R9/R11: gemm0 TM=64/TN=128
// grid(270,4), gemm12 BK=64 -> 155.8us best. R10 (failed): BK=32 doubled
// barriers. R12: plan_k removed -- consumers derive plan from bcnt.
// R13 (this): gemm12 was 1 blk/CU + 1 wave/SIMD + serial stage->drain->MFMA
// (zero overlap). Now 512 thr (2 waves/SIMD) + explicit LDS double-buffer,
// ONE barrier per kb (prefetch kb+1 under kb's MFMAs), sT2 staged under
// kb=7. Plan broadcast: xc_k block0 writes 22-int plan{tot,padoff,cumt};
// gemms load it instead of scanning 448-int bcnt serially per block.

#define BATCH   16384
#define NSCENE  7
#define TM      128
#define NBLK    (BATCH / 256)            // 64 count blocks
#define MT_MAX  (BATCH / TM + NSCENE)    // 135 worst-case tiles
#define PADMAX  (BATCH + NSCENE * TM)    // 17280 padded rows max

typedef __bf16 bf16x8 __attribute__((ext_vector_type(8)));
typedef float  f32x4  __attribute__((ext_vector_type(4)));

__device__ __forceinline__ ushort f2bf(float f) {
  union { float f; uint32_t u; } v; v.f = f;
  uint32_t r = (v.u + 0x7FFFu + ((v.u >> 16) & 1u)) >> 16;  // RNE
  return (ushort)r;
}
__device__ __forceinline__ uint32_t pk2(float a, float b) {
  union { __hip_bfloat162 h; uint32_t u; } cv;
  cv.h = __float22bfloat162_rn(make_float2(a, b));   // v_cvt_pk_bf16_f32
  return cv.u;
}
__device__ __forceinline__ void async16(const void* g, void* lds) {
  __builtin_amdgcn_global_load_lds(
      (const __attribute__((address_space(1))) uint32_t*)g,
      (__attribute__((address_space(3))) uint32_t*)lds, 16, 0, 0);
}

// ---- fused prep: W scale+transpose (x3), bias fuse, count+rank -----------
__device__ __forceinline__ void st_tile(const float* __restrict__ W,
                                        const float* __restrict__ gW,
                                        ushort* __restrict__ sT,
                                        int K, int N, int s, int n0, int k0,
                                        int tid) {
  __shared__ float tl[32][33];
  int tx = tid & 31, ty = tid >> 5;
  const float* Wp = W + (size_t)s * K * N;
#pragma unroll
  for (int i = 0; i < 4; i++) {
    int k = k0 + ty + i * 8;
    tl[ty + i * 8][tx] = Wp[(size_t)k * N + n0 + tx] * gW[(size_t)k * N + n0 + tx];
  }
  __syncthreads();
#pragma unroll
  for (int i = 0; i < 4; i++) {
    int n = n0 + ty + i * 8;
    sT[((size_t)s * N + n) * K + k0 + tx] = f2bf(tl[tx][ty + i * 8]);
  }
}

#define NB_W0 (16 * 16 * 7)
#define NB_W1 (8 * 16 * 7)
#define NB_W2 (2 * 8 * 7)
#define NB_BIAS 23
#define NB_CNT NBLK

__global__ __launch_bounds__(256) void prep_k(
    const float* __restrict__ W0, const float* __restrict__ gW0,
    const float* __restrict__ W1, const float* __restrict__ gW1,
    const float* __restrict__ W2, const float* __restrict__ gW2,
    const float* __restrict__ b0, const float* __restrict__ gb0,
    const float* __restrict__ b1, const float* __restrict__ gb1,
    const float* __restrict__ b2, const float* __restrict__ gb2,
    const int* __restrict__ scene,
    ushort* __restrict__ sT0, ushort* __restrict__ sT1, ushort* __restrict__ sT2,
    float* __restrict__ bias0, float* __restrict__ bias1, float* __restrict__ bias2,
    int* __restrict__ bcnt, int* __restrict__ rank) {
  int bid = blockIdx.x, tid = threadIdx.x;
  if (bid < NB_W0) {
    int l = bid;
    st_tile(W0, gW0, sT0, 512, 512, l / 256, (l % 16) * 32, ((l / 16) % 16) * 32, tid);
  } else if (bid < NB_W0 + NB_W1) {
    int l = bid - NB_W0;
    st_tile(W1, gW1, sT1, 512, 256, l / 128, (l % 8) * 32, ((l / 8) % 16) * 32, tid);
  } else if (bid < NB_W0 + NB_W1 + NB_W2) {
    int l = bid - NB_W0 - NB_W1;
    st_tile(W2, gW2, sT2, 256, 64, l / 16, (l % 2) * 32, ((l / 2) % 8) * 32, tid);
  } else if (bid < NB_W0 + NB_W1 + NB_W2 + NB_BIAS) {
    int t = (bid - NB_W0 - NB_W1 - NB_W2) * 256 + tid;
    if (t < 7 * 512) bias0[t] = b0[t] + gb0[t & 511];
    else if (t < 7 * 512 + 7 * 256) { int i = t - 7 * 512; bias1[i] = b1[i] + gb1[i & 255]; }
    else if (t < 7 * 512 + 7 * 256 + 7 * 64) { int i = t - 7 * 512 - 7 * 256; bias2[i] = b2[i] + gb2[i & 63]; }
  } else {
    __shared__ int l[NSCENE];
    if (tid < NSCENE) l[tid] = 0;
    __syncthreads();
    int blk = bid - NB_W0 - NB_W1 - NB_W2 - NB_BIAS;
    int i = blk * 256 + tid;
    int pos = atomicAdd(&l[scene[i] - 1], 1);   // LDS atomic: rank in block
    rank[i] = pos;
    __syncthreads();
    if (tid < NSCENE) bcnt[blk * NSCENE + tid] = l[tid];
  }
}

// ---- full per-block plan derivation (xc_k only; gemms read 22-int plan) --
#define PLAN_SHARED  __shared__ int sb[NBLK * NSCENE]; \
                     __shared__ int tot[NSCENE], padoff[NSCENE], cumt[NSCENE + 1];
__device__ __forceinline__ void plan_derive(const int* __restrict__ bcnt,
                                            int* sb, int* tot, int* padoff,
                                            int* cumt, int tid) {
  if (tid < NBLK * NSCENE) sb[tid] = bcnt[tid];
  if (tid + 256 < NBLK * NSCENE) sb[tid + 256] = bcnt[tid + 256];
  __syncthreads();
  if (tid < NSCENE) {
    int c = 0;
    for (int b = 0; b < NBLK; b++) c += sb[b * NSCENE + tid];
    tot[tid] = c;
  }
  __syncthreads();
  if (tid == 0) {
    int po = 0, ct = 0;
    for (int s = 0; s < NSCENE; s++) {
      padoff[s] = po; cumt[s] = ct;
      int tiles = (tot[s] + TM - 1) / TM;
      ct += tiles; po += tiles * TM;
    }
    cumt[NSCENE] = ct;
  }
  __syncthreads();
}

// ---- xc: compact + fp32->bf16 convert x, write idxp + 22-int plan --------
// plan layout: [0..6]=tot, [7..13]=padoff, [14..21]=cumt
__global__ __launch_bounds__(256) void xc_k(const float* __restrict__ x,
                                            const int* __restrict__ scene,
                                            const int* __restrict__ rank,
                                            const int* __restrict__ bcnt,
                                            int* __restrict__ idxp,
                                            ushort* __restrict__ xc,
                                            int* __restrict__ plan_g) {
  PLAN_SHARED
  __shared__ int base7[NSCENE];
  int tid = threadIdx.x;
  plan_derive(bcnt, sb, tot, padoff, cumt, tid);
  if (blockIdx.x == 0) {
    if (tid < NSCENE) { plan_g[tid] = tot[tid]; plan_g[7 + tid] = padoff[tid]; }
    if (tid < NSCENE + 1) plan_g[14 + tid] = cumt[tid];
  }
  int myblk = blockIdx.x >> 5;      // this block's 8 rows share a count-block
  if (tid < NSCENE) {
    int pre = 0;
    for (int b = 0; b < myblk; b++) pre += sb[b * NSCENE + tid];
    base7[tid] = padoff[tid] + pre;
  }
  __syncthreads();

  int r = blockIdx.x * 8 + (tid >> 5);
  int s = scene[r] - 1;
  int d = base7[s] + rank[r];
  if ((tid & 31) == 0) idxp[d] = r;
  int c = (tid & 31) * 16;
  const float4* p = (const float4*)(x + (size_t)r * 512 + c);
  float4 f0 = p[0], f1 = p[1], f2 = p[2], f3 = p[3];
  uint4 v0, v1;
  v0.x = pk2(f0.x, f0.y); v0.y = pk2(f0.z, f0.w);
  v0.z = pk2(f1.x, f1.y); v0.w = pk2(f1.z, f1.w);
  v1.x = pk2(f2.x, f2.y); v1.y = pk2(f2.z, f2.w);
  v1.z = pk2(f3.x, f3.y); v1.w = pk2(f3.z, f3.w);
  uint4* q = (uint4*)(xc + (size_t)d * 512 + c);
  q[0] = v0; q[1] = v1;
}

// ---- L0 GEMM: hc1 = relu(xc @ sT0^T + bias0), TM=64 x TN=128 -------------
// 1080 blocks, ~24KB LDS -> ~5-6 blk/CU; implicit inter-block overlap
// (m114) already hides DMA here, so structure unchanged (m99/m100: explicit
// dbuf neutral at >=3 blk/CU). R13: plan scan replaced by 22-int load.
__global__ __launch_bounds__(256) void gemm0_k(
    const ushort* __restrict__ ain, const ushort* __restrict__ bw,
    const float* __restrict__ bias, const int* __restrict__ plan,
    ushort* __restrict__ hout) {
  __shared__ int splan[24];
  __shared__ __align__(16) ushort Abuf[64 * 64];    // 8 KB
  __shared__ __align__(16) ushort Bbuf[128 * 64];   // 16 KB

  int tid = threadIdx.x;
  if (tid < 22) splan[tid] = plan[tid];
  __syncthreads();
  const int* padoff = splan + 7;
  const int* cumt   = splan + 14;

  int j = blockIdx.x;
  int t = j >> 1;
  if (t >= cumt[NSCENE]) return;
  int sc = 0;
  while (sc < NSCENE - 1 && t >= cumt[sc + 1]) sc++;
  int mrow0 = padoff[sc] + (t - cumt[sc]) * TM + (j & 1) * 64;
  int nb = blockIdx.y;

  int lane = tid & 63, wid = tid >> 6;   // wave covers 32 cols, all 64 rows

  f32x4 acc[4][2];
#pragma unroll
  for (int mt = 0; mt < 4; mt++)
#pragma unroll
    for (int nt = 0; nt < 2; nt++) acc[mt][nt] = (f32x4){0.f, 0.f, 0.f, 0.f};

  const ushort* bwS = bw + ((size_t)sc * 512 + (size_t)nb * 128) * 512;

  for (int kb = 0; kb < 8; kb++) {
#pragma unroll
    for (int i = 0; i < 2; i++) {             // A tile (64 x 64): 512 chunks
      int c = tid + i * 256;
      int row = c >> 3, q = c & 7;
      int kg = q ^ (row & 7);
      async16(ain + (size_t)(mrow0 + row) * 512 + kb * 64 + kg * 8,
              &Abuf[(size_t)(i * 256 + wid * 64) * 8]);
    }
#pragma unroll
    for (int i = 0; i < 4; i++) {             // B tile (128 x 64): 1024 chunks
      int c = tid + i * 256;
      int row = c >> 3, q = c & 7;
      int kg = q ^ (row & 7);
      async16(bwS + (size_t)row * 512 + kb * 64 + kg * 8,
              &Bbuf[(size_t)(i * 256 + wid * 64) * 8]);
    }
    __syncthreads();
#pragma unroll
    for (int kk = 0; kk < 64; kk += 32) {
      bf16x8 af[4], bfr[2];
      int kc = (kk >> 3) + (lane >> 4);
#pragma unroll
      for (int mt = 0; mt < 4; mt++) {
        int row = mt * 16 + (lane & 15);
        af[mt] = *(const bf16x8*)(&Abuf[(row * 8 + (kc ^ (row & 7))) * 8]);
      }
#pragma unroll
      for (int nt = 0; nt < 2; nt++) {
        int row = wid * 32 + nt * 16 + (lane & 15);
        bfr[nt] = *(const bf16x8*)(&Bbuf[(row * 8 + (kc ^ (row & 7))) * 8]);
      }
#pragma unroll
      for (int mt = 0; mt < 4; mt++)
#pragma unroll
        for (int nt = 0; nt < 2; nt++)
          acc[mt][nt] = __builtin_amdgcn_mfma_f32_16x16x32_bf16(af[mt], bfr[nt], acc[mt][nt], 0, 0, 0);
    }
    __syncthreads();
  }

  // epilogue: C/D layout col=lane&15, row=(lane>>4)*4+reg [m89-verified]
#pragma unroll
  for (int mt = 0; mt < 4; mt++) {
    int rl0 = mt * 16 + (lane >> 4) * 4;
#pragma unroll
    for (int nt = 0; nt < 2; nt++) {
      int col = nb * 128 + wid * 32 + nt * 16 + (lane & 15);
      float bv = bias[sc * 512 + col];
#pragma unroll
      for (int r = 0; r < 4; r++) {
        float v = fmaxf(acc[mt][nt][r] + bv, 0.f);
        hout[(size_t)(mrow0 + rl0 + r) * 512 + col] = f2bf(v);
      }
    }
  }
}

// ---- gemm12 staging helpers (512 threads) --------------------------------
__device__ __forceinline__ void stage_ab12(const ushort* __restrict__ ain,
                                           const ushort* __restrict__ bw,
                                           ushort* Ab, ushort* Bb,
                                           int mrow0, int kb, int tid, int wid) {
  {                                           // A tile (64 x 64): 512 chunks
    int c = tid, row = c >> 3, q = c & 7;
    int kg = q ^ (row & 7);
    async16(ain + (size_t)(mrow0 + row) * 512 + kb * 64 + kg * 8,
            Ab + (size_t)(wid * 64) * 8);
  }
#pragma unroll
  for (int i = 0; i < 4; i++) {               // B tile (256 x 64): 2048 chunks
    int c = tid + i * 512, row = c >> 3, q = c & 7;
    int kg = q ^ (row & 7);
    async16(bw + (size_t)row * 512 + kb * 64 + kg * 8,
            Bb + (size_t)(i * 512 + wid * 64) * 8);
  }
}
__device__ __forceinline__ void stage_b2f(const ushort* __restrict__ b2p,
                                          ushort* Bb, int tid, int wid) {
#pragma unroll
  for (int i = 0; i < 4; i++) {               // 64 rows x 32 chunks = 2048
    int p = tid + i * 512, row = p >> 5, pc = p & 31;
    int kg = pc ^ (row & 7);
    async16(b2p + (size_t)row * 256 + kg * 8,
            Bb + (size_t)(i * 512 + wid * 64) * 8);
  }
}

// ---- fused L1+L2, TM=64: h2 = relu(hc1 @ sT1^T + b1) in LDS;
//      out = h2 @ sT2^T + b2.
// R13: 512 thr (8 waves, 2/SIMD), explicit double-buffer, ONE barrier/kb.
// Per kb: prefetch kb+1 (or sT2 at kb=7) -> compute kb -> sync (drain).
// LDS: A 2x8K + B 2x32K + B2 32K + h2 32K = 144 KB -> 1 blk/CU (grid 270).
__global__ __launch_bounds__(512, 2) void gemm12_k(
    const ushort* __restrict__ hc1, const ushort* __restrict__ sT1,
    const ushort* __restrict__ sT2, const float* __restrict__ bias1,
    const float* __restrict__ bias2, const int* __restrict__ plan,
    const int* __restrict__ idxp, float* __restrict__ out) {
  __shared__ int splan[24];
  __shared__ __align__(16) ushort Abuf[2][64 * 64];    // 16 KB
  __shared__ __align__(16) ushort Bbuf[2][256 * 64];   // 64 KB
  __shared__ __align__(16) ushort B2buf[64 * 256];     // 32 KB
  __shared__ __align__(16) ushort h2[64 * 256];        // 32 KB

  int tid = threadIdx.x;
  if (tid < 22) splan[tid] = plan[tid];
  __syncthreads();
  const int* tot    = splan;
  const int* padoff = splan + 7;
  const int* cumt   = splan + 14;

  int j = blockIdx.x;
  int t = j >> 1;
  if (t >= cumt[NSCENE]) return;
  int sc = 0;
  while (sc < NSCENE - 1 && t >= cumt[sc + 1]) sc++;
  int mrow0 = padoff[sc] + (t - cumt[sc]) * TM + (j & 1) * 64;
  int maxloc = padoff[sc] + tot[sc];   // rows >= maxloc are pads
  if (mrow0 >= maxloc) return;         // all-pad half-tile: nothing to emit

  int lane = tid & 63, wid = tid >> 6;   // 8 waves; wave covers 32 cols (L1)

  const ushort* b1p = sT1 + (size_t)sc * 256 * 512;
  const ushort* b2p = sT2 + (size_t)sc * 64 * 256;

  // ---- phase 1: L1 (64 x 256, K=512), wave tile 64x32, double-buffered ----
  f32x4 acc[4][2];
#pragma unroll
  for (int mt = 0; mt < 4; mt++)
#pragma unroll
    for (int nt = 0; nt < 2; nt++) acc[mt][nt] = (f32x4){0.f, 0.f, 0.f, 0.f};

  stage_ab12(hc1, b1p, Abuf[0], Bbuf[0], mrow0, 0, tid, wid);
  __syncthreads();                      // drain kb=0 DMA

  for (int kb = 0; kb < 8; kb++) {
    const ushort* Ac = Abuf[kb & 1];
    const ushort* Bc = Bbuf[kb & 1];
    if (kb < 7)                         // prefetch next tile under compute
      stage_ab12(hc1, b1p, Abuf[(kb & 1) ^ 1], Bbuf[(kb & 1) ^ 1],
                 mrow0, kb + 1, tid, wid);
    else                                // last tile: prestage sT2 for phase 2
      stage_b2f(b2p, B2buf, tid, wid);
#pragma unroll
    for (int kk = 0; kk < 64; kk += 32) {
      bf16x8 af[4], bfr[2];
      int kc = (kk >> 3) + (lane >> 4);
#pragma unroll
      for (int mt = 0; mt < 4; mt++) {
        int row = mt * 16 + (lane & 15);
        af[mt] = *(const bf16x8*)(&Ac[(row * 8 + (kc ^ (row & 7))) * 8]);
      }
#pragma unroll
      for (int nt = 0; nt < 2; nt++) {
        int row = wid * 32 + nt * 16 + (lane & 15);
        bfr[nt] = *(const bf16x8*)(&Bc[(row * 8 + (kc ^ (row & 7))) * 8]);
      }
#pragma unroll
      for (int mt = 0; mt < 4; mt++)
#pragma unroll
        for (int nt = 0; nt < 2; nt++)
          acc[mt][nt] = __builtin_amdgcn_mfma_f32_16x16x32_bf16(af[mt], bfr[nt], acc[mt][nt], 0, 0, 0);
    }
    __syncthreads();                    // drains prefetch DMA + LDS reads
  }

  // epilogue 1 -> h2 LDS, XOR-swizzled 16B chunks
#pragma unroll
  for (int mt = 0; mt < 4; mt++) {
#pragma unroll
    for (int nt = 0; nt < 2; nt++) {
      int col = wid * 32 + nt * 16 + (lane & 15);
      float bv = bias1[sc * 256 + col];
#pragma unroll
      for (int r = 0; r < 4; r++) {
        int row = mt * 16 + (lane >> 4) * 4 + r;
        float v = fmaxf(acc[mt][nt][r] + bv, 0.f);
        h2[(row * 32 + ((col >> 3) ^ (row & 7))) * 8 + (col & 7)] = f2bf(v);
      }
    }
  }
  __syncthreads();

  // ---- phase 2: L2 (64 x 64, K=256); B2 already resident in LDS ----------
  // 8 waves: wave = 16 rows x 32 cols.
  f32x4 acc2[2];
  acc2[0] = (f32x4){0.f, 0.f, 0.f, 0.f};
  acc2[1] = (f32x4){0.f, 0.f, 0.f, 0.f};
  int rbase = (wid >> 1) * 16;
  int cbase = (wid & 1) * 32;
#pragma unroll
  for (int kk = 0; kk < 256; kk += 32) {
    int kf = (kk >> 3) + (lane >> 4);
    int arow = rbase + (lane & 15);
    bf16x8 af = *(const bf16x8*)(&h2[(arow * 32 + (kf ^ (arow & 7))) * 8]);
    bf16x8 bfr[2];
#pragma unroll
    for (int nt = 0; nt < 2; nt++) {
      int n = cbase + nt * 16 + (lane & 15);
      bfr[nt] = *(const bf16x8*)(&B2buf[(n * 32 + (kf ^ (n & 7))) * 8]);
    }
#pragma unroll
    for (int nt = 0; nt < 2; nt++)
      acc2[nt] = __builtin_amdgcn_mfma_f32_16x16x32_bf16(af, bfr[nt], acc2[nt], 0, 0, 0);
  }

  // epilogue 2: scatter fp32 rows via idxp; pad rows (>= maxloc) skipped
  int rowg[4], gidx[4];
#pragma unroll
  for (int r = 0; r < 4; r++) {
    rowg[r] = mrow0 + rbase + (lane >> 4) * 4 + r;
    gidx[r] = idxp[rowg[r]];
  }
#pragma unroll
  for (int nt = 0; nt < 2; nt++) {
    int col = cbase + nt * 16 + (lane & 15);
    float bv = bias2[sc * 64 + col];
#pragma unroll
    for (int r = 0; r < 4; r++) {
      if (rowg[r] < maxloc) out[(size_t)gidx[r] * 64 + col] = acc2[nt][r] + bv;
    }
  }
}

extern "C" void kernel_launch(void* const* d_in, const int* in_sizes, int n_in,
                              void* d_out, int out_size, void* d_ws, size_t ws_size,
                              hipStream_t stream) {
  const float* x   = (const float*)d_in[0];
  const int* scene = (const int*)d_in[1];
  const float* W0  = (const float*)d_in[2];
  const float* b0  = (const float*)d_in[3];
  const float* gW0 = (const float*)d_in[4];
  const float* gb0 = (const float*)d_in[5];
  const float* W1  = (const float*)d_in[6];
  const float* b1  = (const float*)d_in[7];
  const float* gW1 = (const float*)d_in[8];
  const float* gb1 = (const float*)d_in[9];
  const float* W2  = (const float*)d_in[10];
  const float* b2  = (const float*)d_in[11];
  const float* gW2 = (const float*)d_in[12];
  const float* gb2 = (const float*)d_in[13];
  float* out = (float*)d_out;

  char* ws = (char*)d_ws;
  size_t off = 0;
  auto alloc = [&](size_t bytes) -> void* {
    void* p = ws + off;
    off = (off + bytes + 255) & ~(size_t)255;
    return p;
  };
  ushort* sT0   = (ushort*)alloc((size_t)7 * 512 * 512 * 2);
  ushort* sT1   = (ushort*)alloc((size_t)7 * 256 * 512 * 2);
  ushort* sT2   = (ushort*)alloc((size_t)7 * 64 * 256 * 2);
  float*  bias0 = (float*)alloc(7 * 512 * 4);
  float*  bias1 = (float*)alloc(7 * 256 * 4);
  float*  bias2 = (float*)alloc(7 * 64 * 4);
  int*    bcnt  = (int*)alloc(NBLK * NSCENE * 4);
  int*    rank  = (int*)alloc(BATCH * 4);
  int*    idxp  = (int*)alloc(PADMAX * 4);
  int*    plan  = (int*)alloc(32 * 4);
  ushort* xc    = (ushort*)alloc((size_t)PADMAX * 512 * 2);
  ushort* hc1   = (ushort*)alloc((size_t)PADMAX * 512 * 2);
  (void)ws_size; (void)n_in; (void)in_sizes; (void)out_size;

  prep_k<<<NB_W0 + NB_W1 + NB_W2 + NB_BIAS + NB_CNT, 256, 0, stream>>>(
      W0, gW0, W1, gW1, W2, gW2, b0, gb0, b1, gb1, b2, gb2, scene,
      sT0, sT1, sT2, bias0, bias1, bias2, bcnt, rank);
  xc_k<<<BATCH / 8, 256, 0, stream>>>(x, scene, rank, bcnt, idxp, xc, plan);

  gemm0_k<<<dim3(MT_MAX * 2, 4), 256, 0, stream>>>(xc, sT0, bias0, plan, hc1);
  gemm12_k<<<dim3(MT_MAX * 2), 512, 0, stream>>>(hc1, sT1, sT2, bias1, bias2,
                                                 plan, idxp, out);
}

// Round 2
// 156.042 us; speedup vs baseline: 1.0245x; 1.0245x over previous
//
#include <hip/hip_runtime.h>
#include <hip/hip_bf16.h>
#include <stdint.h>

// STAR-DNN: per-sample scene-selected 3-layer MLP.
// R1: LDS-histogram compaction. R2: global_load_lds DMA. R4 (failed): grid
// barrier ~140us on 8 XCDs. R6 (failed): 135-blk fusion starved CUs.
// R8 (failed): gemm0 at 1 blk/CU latency-bound. R9/R11: gemm0 TM=64/TN=128
// grid(270,4), gemm12 BK=64 -> 155.8us best. R10 (failed): BK=32 doubled
// barriers. R12: plan_k removed. R13 (failed, +7.6us): gemm12 512-thr dbuf
// -- per-kb compute (~600cyc) too short to hide 40KB DMA drain; reverted.
// R14 (this): xc_k eliminated. gemm0 gathers A rows directly from x via
// idxp (row-contiguous gather + in-reg fp32->bf16 cvt + swizzled ds_write);
// B stays global_load_lds. Tiny idx_k (64 blocks) writes idxp + 22-int
// plan, zero-fills pad idxp entries. gemm12 = R12 structure + splan load.

#define BATCH   16384
#define NSCENE  7
#define TM      128
#define NBLK    (BATCH / 256)            // 64 count blocks
#define MT_MAX  (BATCH / TM + NSCENE)    // 135 worst-case tiles
#define PADMAX  (BATCH + NSCENE * TM)    // 17280 padded rows max

typedef __bf16 bf16x8 __attribute__((ext_vector_type(8)));
typedef float  f32x4  __attribute__((ext_vector_type(4)));

__device__ __forceinline__ ushort f2bf(float f) {
  union { float f; uint32_t u; } v; v.f = f;
  uint32_t r = (v.u + 0x7FFFu + ((v.u >> 16) & 1u)) >> 16;  // RNE
  return (ushort)r;
}
__device__ __forceinline__ uint32_t pk2(float a, float b) {
  union { __hip_bfloat162 h; uint32_t u; } cv;
  cv.h = __float22bfloat162_rn(make_float2(a, b));   // v_cvt_pk_bf16_f32
  return cv.u;
}
__device__ __forceinline__ void async16(const void* g, void* lds) {
  __builtin_amdgcn_global_load_lds(
      (const __attribute__((address_space(1))) uint32_t*)g,
      (__attribute__((address_space(3))) uint32_t*)lds, 16, 0, 0);
}

// ---- fused prep: W scale+transpose (x3), bias fuse, count+rank -----------
__device__ __forceinline__ void st_tile(const float* __restrict__ W,
                                        const float* __restrict__ gW,
                                        ushort* __restrict__ sT,
                                        int K, int N, int s, int n0, int k0,
                                        int tid) {
  __shared__ float tl[32][33];
  int tx = tid & 31, ty = tid >> 5;
  const float* Wp = W + (size_t)s * K * N;
#pragma unroll
  for (int i = 0; i < 4; i++) {
    int k = k0 + ty + i * 8;
    tl[ty + i * 8][tx] = Wp[(size_t)k * N + n0 + tx] * gW[(size_t)k * N + n0 + tx];
  }
  __syncthreads();
#pragma unroll
  for (int i = 0; i < 4; i++) {
    int n = n0 + ty + i * 8;
    sT[((size_t)s * N + n) * K + k0 + tx] = f2bf(tl[tx][ty + i * 8]);
  }
}

#define NB_W0 (16 * 16 * 7)
#define NB_W1 (8 * 16 * 7)
#define NB_W2 (2 * 8 * 7)
#define NB_BIAS 23
#define NB_CNT NBLK

__global__ __launch_bounds__(256) void prep_k(
    const float* __restrict__ W0, const float* __restrict__ gW0,
    const float* __restrict__ W1, const float* __restrict__ gW1,
    const float* __restrict__ W2, const float* __restrict__ gW2,
    const float* __restrict__ b0, const float* __restrict__ gb0,
    const float* __restrict__ b1, const float* __restrict__ gb1,
    const float* __restrict__ b2, const float* __restrict__ gb2,
    const int* __restrict__ scene,
    ushort* __restrict__ sT0, ushort* __restrict__ sT1, ushort* __restrict__ sT2,
    float* __restrict__ bias0, float* __restrict__ bias1, float* __restrict__ bias2,
    int* __restrict__ bcnt, int* __restrict__ rank) {
  int bid = blockIdx.x, tid = threadIdx.x;
  if (bid < NB_W0) {
    int l = bid;
    st_tile(W0, gW0, sT0, 512, 512, l / 256, (l % 16) * 32, ((l / 16) % 16) * 32, tid);
  } else if (bid < NB_W0 + NB_W1) {
    int l = bid - NB_W0;
    st_tile(W1, gW1, sT1, 512, 256, l / 128, (l % 8) * 32, ((l / 8) % 16) * 32, tid);
  } else if (bid < NB_W0 + NB_W1 + NB_W2) {
    int l = bid - NB_W0 - NB_W1;
    st_tile(W2, gW2, sT2, 256, 64, l / 16, (l % 2) * 32, ((l / 2) % 8) * 32, tid);
  } else if (bid < NB_W0 + NB_W1 + NB_W2 + NB_BIAS) {
    int t = (bid - NB_W0 - NB_W1 - NB_W2) * 256 + tid;
    if (t < 7 * 512) bias0[t] = b0[t] + gb0[t & 511];
    else if (t < 7 * 512 + 7 * 256) { int i = t - 7 * 512; bias1[i] = b1[i] + gb1[i & 255]; }
    else if (t < 7 * 512 + 7 * 256 + 7 * 64) { int i = t - 7 * 512 - 7 * 256; bias2[i] = b2[i] + gb2[i & 63]; }
  } else {
    __shared__ int l[NSCENE];
    if (tid < NSCENE) l[tid] = 0;
    __syncthreads();
    int blk = bid - NB_W0 - NB_W1 - NB_W2 - NB_BIAS;
    int i = blk * 256 + tid;
    int pos = atomicAdd(&l[scene[i] - 1], 1);   // LDS atomic: rank in block
    rank[i] = pos;
    __syncthreads();
    if (tid < NSCENE) bcnt[blk * NSCENE + tid] = l[tid];
  }
}

// ---- full plan derivation (idx_k only; gemms read 22-int plan) -----------
#define PLAN_SHARED  __shared__ int sb[NBLK * NSCENE]; \
                     __shared__ int tot[NSCENE], padoff[NSCENE], cumt[NSCENE + 1];
__device__ __forceinline__ void plan_derive(const int* __restrict__ bcnt,
                                            int* sb, int* tot, int* padoff,
                                            int* cumt, int tid) {
  if (tid < NBLK * NSCENE) sb[tid] = bcnt[tid];
  if (tid + 256 < NBLK * NSCENE) sb[tid + 256] = bcnt[tid + 256];
  __syncthreads();
  if (tid < NSCENE) {
    int c = 0;
    for (int b = 0; b < NBLK; b++) c += sb[b * NSCENE + tid];
    tot[tid] = c;
  }
  __syncthreads();
  if (tid == 0) {
    int po = 0, ct = 0;
    for (int s = 0; s < NSCENE; s++) {
      padoff[s] = po; cumt[s] = ct;
      int tiles = (tot[s] + TM - 1) / TM;
      ct += tiles; po += tiles * TM;
    }
    cumt[NSCENE] = ct;
  }
  __syncthreads();
}

// ---- idx_k: 64 blocks; write idxp (compacted row index), 22-int plan -----
// plan layout: [0..6]=tot, [7..13]=padoff, [14..21]=cumt
__global__ __launch_bounds__(256) void idx_k(const int* __restrict__ scene,
                                             const int* __restrict__ rank,
                                             const int* __restrict__ bcnt,
                                             int* __restrict__ idxp,
                                             int* __restrict__ plan_g) {
  PLAN_SHARED
  __shared__ int base7[NSCENE];
  int tid = threadIdx.x;
  plan_derive(bcnt, sb, tot, padoff, cumt, tid);
  int myblk = blockIdx.x;
  if (tid < NSCENE) {
    int pre = 0;
    for (int b = 0; b < myblk; b++) pre += sb[b * NSCENE + tid];
    base7[tid] = padoff[tid] + pre;
  }
  __syncthreads();
  int r = myblk * 256 + tid;
  idxp[base7[scene[r] - 1] + rank[r]] = r;
  if (myblk == 0) {
    if (tid < NSCENE) { plan_g[tid] = tot[tid]; plan_g[7 + tid] = padoff[tid]; }
    if (tid < NSCENE + 1) plan_g[14 + tid] = cumt[tid];
    // zero-fill pad idxp entries so gemm0's A-gather stays in-bounds
    for (int s = 0; s < NSCENE; s++) {
      int lo = padoff[s] + tot[s];
      int hi = (s + 1 < NSCENE) ? padoff[s + 1] : cumt[NSCENE] * TM;
      for (int i = lo + tid; i < hi; i += 256) idxp[i] = 0;
    }
  }
}

// ---- L0 GEMM: hc1 = relu(x[idxp] @ sT0^T + bias0), TM=64 x TN=128 --------
// 1080 blocks, ~24KB LDS -> ~4 blk/CU implicit overlap (m114). R14: A is
// gathered straight from fp32 x (row-contiguous, 64B/thread) + cvt_pk +
// XOR-swizzled ds_write (2-way bank = free, m136); B stays DMA. xc removed.
__global__ __launch_bounds__(256) void gemm0_k(
    const float* __restrict__ x, const int* __restrict__ idxp,
    const ushort* __restrict__ bw, const float* __restrict__ bias,
    const int* __restrict__ plan, ushort* __restrict__ hout) {
  __shared__ int splan[24];
  __shared__ int sidx[64];
  __shared__ __align__(16) ushort Abuf[64 * 64];    // 8 KB
  __shared__ __align__(16) ushort Bbuf[128 * 64];   // 16 KB

  int tid = threadIdx.x;
  if (tid < 22) splan[tid] = plan[tid];
  __syncthreads();
  const int* padoff = splan + 7;
  const int* cumt   = splan + 14;

  int j = blockIdx.x;
  int t = j >> 1;
  if (t >= cumt[NSCENE]) return;
  int sc = 0;
  while (sc < NSCENE - 1 && t >= cumt[sc + 1]) sc++;
  int mrow0 = padoff[sc] + (t - cumt[sc]) * TM + (j & 1) * 64;
  int nb = blockIdx.y;

  if (tid < 64) sidx[tid] = idxp[mrow0 + tid];
  __syncthreads();

  int lane = tid & 63, wid = tid >> 6;   // wave covers 32 cols, all 64 rows
  int arow = tid >> 2, aq = tid & 3;     // A-gather: 4 thr/row, 16 floats each
  const float* xp = x + (size_t)sidx[arow] * 512 + aq * 16;
  ushort* awr0 = &Abuf[((size_t)arow * 8 + ((2 * aq) ^ (arow & 7))) * 8];
  ushort* awr1 = &Abuf[((size_t)arow * 8 + ((2 * aq + 1) ^ (arow & 7))) * 8];

  f32x4 acc[4][2];
#pragma unroll
  for (int mt = 0; mt < 4; mt++)
#pragma unroll
    for (int nt = 0; nt < 2; nt++) acc[mt][nt] = (f32x4){0.f, 0.f, 0.f, 0.f};

  const ushort* bwS = bw + ((size_t)sc * 512 + (size_t)nb * 128) * 512;

  for (int kb = 0; kb < 8; kb++) {
#pragma unroll
    for (int i = 0; i < 4; i++) {             // B tile (128 x 64): DMA first
      int c = tid + i * 256;
      int row = c >> 3, q = c & 7;
      int kg = q ^ (row & 7);
      async16(bwS + (size_t)row * 512 + kb * 64 + kg * 8,
              &Bbuf[(size_t)(i * 256 + wid * 64) * 8]);
    }
    {                                         // A gather + cvt under B DMA
      const float4* ap = (const float4*)(xp + kb * 64);
      float4 f0 = ap[0], f1 = ap[1], f2 = ap[2], f3 = ap[3];
      uint4 u0, u1;
      u0.x = pk2(f0.x, f0.y); u0.y = pk2(f0.z, f0.w);
      u0.z = pk2(f1.x, f1.y); u0.w = pk2(f1.z, f1.w);
      u1.x = pk2(f2.x, f2.y); u1.y = pk2(f2.z, f2.w);
      u1.z = pk2(f3.x, f3.y); u1.w = pk2(f3.z, f3.w);
      *(uint4*)awr0 = u0;
      *(uint4*)awr1 = u1;
    }
    __syncthreads();
#pragma unroll
    for (int kk = 0; kk < 64; kk += 32) {
      bf16x8 af[4], bfr[2];
      int kc = (kk >> 3) + (lane >> 4);
#pragma unroll
      for (int mt = 0; mt < 4; mt++) {
        int row = mt * 16 + (lane & 15);
        af[mt] = *(const bf16x8*)(&Abuf[(row * 8 + (kc ^ (row & 7))) * 8]);
      }
#pragma unroll
      for (int nt = 0; nt < 2; nt++) {
        int row = wid * 32 + nt * 16 + (lane & 15);
        bfr[nt] = *(const bf16x8*)(&Bbuf[(row * 8 + (kc ^ (row & 7))) * 8]);
      }
#pragma unroll
      for (int mt = 0; mt < 4; mt++)
#pragma unroll
        for (int nt = 0; nt < 2; nt++)
          acc[mt][nt] = __builtin_amdgcn_mfma_f32_16x16x32_bf16(af[mt], bfr[nt], acc[mt][nt], 0, 0, 0);
    }
    __syncthreads();
  }

  // epilogue: C/D layout col=lane&15, row=(lane>>4)*4+reg [m89-verified]
#pragma unroll
  for (int mt = 0; mt < 4; mt++) {
    int rl0 = mt * 16 + (lane >> 4) * 4;
#pragma unroll
    for (int nt = 0; nt < 2; nt++) {
      int col = nb * 128 + wid * 32 + nt * 16 + (lane & 15);
      float bv = bias[sc * 512 + col];
#pragma unroll
      for (int r = 0; r < 4; r++) {
        float v = fmaxf(acc[mt][nt][r] + bv, 0.f);
        hout[(size_t)(mrow0 + rl0 + r) * 512 + col] = f2bf(v);
      }
    }
  }
}

// ---- fused L1+L2, TM=64 (R12 structure): h2 = relu(hc1 @ sT1^T + b1) in
//      LDS; out = h2 @ sT2^T + b2. 256 thr, BK=64, ~72 KB LDS.
__global__ __launch_bounds__(256) void gemm12_k(
    const ushort* __restrict__ hc1, const ushort* __restrict__ sT1,
    const ushort* __restrict__ sT2, const float* __restrict__ bias1,
    const float* __restrict__ bias2, const int* __restrict__ plan,
    const int* __restrict__ idxp, float* __restrict__ out) {
  __shared__ int splan[24];
  __shared__ __align__(16) ushort Abuf[64 * 64];    // 8 KB
  __shared__ __align__(16) ushort Bbuf[256 * 64];   // 32 KB
  __shared__ __align__(16) ushort h2[64 * 256];     // 32 KB

  int tid = threadIdx.x;
  if (tid < 22) splan[tid] = plan[tid];
  __syncthreads();
  const int* tot    = splan;
  const int* padoff = splan + 7;
  const int* cumt   = splan + 14;

  int j = blockIdx.x;
  int t = j >> 1;
  if (t >= cumt[NSCENE]) return;
  int sc = 0;
  while (sc < NSCENE - 1 && t >= cumt[sc + 1]) sc++;
  int mrow0 = padoff[sc] + (t - cumt[sc]) * TM + (j & 1) * 64;
  int maxloc = padoff[sc] + tot[sc];   // rows >= maxloc are pads
  if (mrow0 >= maxloc) return;         // all-pad half-tile

  int lane = tid & 63, wid = tid >> 6;   // wave n-index

  // ---- phase 1: L1 (64 x 256, K=512), wave tile 64x64 ----
  f32x4 acc[4][4];
#pragma unroll
  for (int mt = 0; mt < 4; mt++)
#pragma unroll
    for (int nt = 0; nt < 4; nt++) acc[mt][nt] = (f32x4){0.f, 0.f, 0.f, 0.f};

  const ushort* b1p = sT1 + (size_t)sc * 256 * 512;

  for (int kb = 0; kb < 8; kb++) {
#pragma unroll
    for (int i = 0; i < 2; i++) {             // A tile (64 x 64): 512 chunks
      int c = tid + i * 256;
      int row = c >> 3, q = c & 7;
      int kg = q ^ (row & 7);
      async16(hc1 + (size_t)(mrow0 + row) * 512 + kb * 64 + kg * 8,
              &Abuf[(size_t)(i * 256 + wid * 64) * 8]);
    }
#pragma unroll
    for (int i = 0; i < 8; i++) {             // B tile (256 x 64): 2048 chunks
      int c = tid + i * 256;
      int row = c >> 3, q = c & 7;
      int kg = q ^ (row & 7);
      async16(b1p + (size_t)row * 512 + kb * 64 + kg * 8,
              &Bbuf[(size_t)(i * 256 + wid * 64) * 8]);
    }
    __syncthreads();
#pragma unroll
    for (int kk = 0; kk < 64; kk += 32) {
      bf16x8 af[4], bfr[4];
      int kc = (kk >> 3) + (lane >> 4);
#pragma unroll
      for (int mt = 0; mt < 4; mt++) {
        int row = mt * 16 + (lane & 15);
        af[mt] = *(const bf16x8*)(&Abuf[(row * 8 + (kc ^ (row & 7))) * 8]);
      }
#pragma unroll
      for (int nt = 0; nt < 4; nt++) {
        int row = wid * 64 + nt * 16 + (lane & 15);
        bfr[nt] = *(const bf16x8*)(&Bbuf[(row * 8 + (kc ^ (row & 7))) * 8]);
      }
#pragma unroll
      for (int mt = 0; mt < 4; mt++)
#pragma unroll
        for (int nt = 0; nt < 4; nt++)
          acc[mt][nt] = __builtin_amdgcn_mfma_f32_16x16x32_bf16(af[mt], bfr[nt], acc[mt][nt], 0, 0, 0);
    }
    __syncthreads();
  }

  // epilogue 1 -> h2 LDS, XOR-swizzled 16B chunks
#pragma unroll
  for (int mt = 0; mt < 4; mt++) {
#pragma unroll
    for (int nt = 0; nt < 4; nt++) {
      int col = wid * 64 + nt * 16 + (lane & 15);
      float bv = bias1[sc * 256 + col];
#pragma unroll
      for (int r = 0; r < 4; r++) {
        int row = mt * 16 + (lane >> 4) * 4 + r;
        float v = fmaxf(acc[mt][nt][r] + bv, 0.f);
        h2[(row * 32 + ((col >> 3) ^ (row & 7))) * 8 + (col & 7)] = f2bf(v);
      }
    }
  }

  // ---- phase 2: L2 (64 x 64, K=256); stage full sT2 slice (32 KB) once ----
  const ushort* b2p = sT2 + (size_t)sc * 64 * 256;
#pragma unroll
  for (int i = 0; i < 8; i++) {               // 64 rows x 32 chunks
    int p = tid + i * 256;
    int row = p >> 5, pc = p & 31;
    int kg = pc ^ (row & 7);
    async16(b2p + (size_t)row * 256 + kg * 8,
            &Bbuf[(size_t)(i * 256 + wid * 64) * 8]);
  }
  __syncthreads();

  f32x4 acc2[4];
#pragma unroll
  for (int nt = 0; nt < 4; nt++) acc2[nt] = (f32x4){0.f, 0.f, 0.f, 0.f};

#pragma unroll
  for (int kk = 0; kk < 256; kk += 32) {
    int kf = (kk >> 3) + (lane >> 4);
    bf16x8 af;
    {
      int row = wid * 16 + (lane & 15);       // wave owns 16 output rows
      af = *(const bf16x8*)(&h2[(row * 32 + (kf ^ (row & 7))) * 8]);
    }
    bf16x8 bfr[4];
#pragma unroll
    for (int nt = 0; nt < 4; nt++) {
      int n = nt * 16 + (lane & 15);
      bfr[nt] = *(const bf16x8*)(&Bbuf[(n * 32 + (kf ^ (n & 7))) * 8]);
    }
#pragma unroll
    for (int nt = 0; nt < 4; nt++)
      acc2[nt] = __builtin_amdgcn_mfma_f32_16x16x32_bf16(af, bfr[nt], acc2[nt], 0, 0, 0);
  }

  // epilogue 2: scatter fp32 rows via idxp; pad rows (>= maxloc) skipped
  int rowg[4], gidx[4];
#pragma unroll
  for (int r = 0; r < 4; r++) {
    rowg[r] = mrow0 + wid * 16 + (lane >> 4) * 4 + r;
    gidx[r] = idxp[rowg[r]];
  }
#pragma unroll
  for (int nt = 0; nt < 4; nt++) {
    int col = nt * 16 + (lane & 15);
    float bv = bias2[sc * 64 + col];
#pragma unroll
    for (int r = 0; r < 4; r++) {
      if (rowg[r] < maxloc) out[(size_t)gidx[r] * 64 + col] = acc2[nt][r] + bv;
    }
  }
}

extern "C" void kernel_launch(void* const* d_in, const int* in_sizes, int n_in,
                              void* d_out, int out_size, void* d_ws, size_t ws_size,
                              hipStream_t stream) {
  const float* x   = (const float*)d_in[0];
  const int* scene = (const int*)d_in[1];
  const float* W0  = (const float*)d_in[2];
  const float* b0  = (const float*)d_in[3];
  const float* gW0 = (const float*)d_in[4];
  const float* gb0 = (const float*)d_in[5];
  const float* W1  = (const float*)d_in[6];
  const float* b1  = (const float*)d_in[7];
  const float* gW1 = (const float*)d_in[8];
  const float* gb1 = (const float*)d_in[9];
  const float* W2  = (const float*)d_in[10];
  const float* b2  = (const float*)d_in[11];
  const float* gW2 = (const float*)d_in[12];
  const float* gb2 = (const float*)d_in[13];
  float* out = (float*)d_out;

  char* ws = (char*)d_ws;
  size_t off = 0;
  auto alloc = [&](size_t bytes) -> void* {
    void* p = ws + off;
    off = (off + bytes + 255) & ~(size_t)255;
    return p;
  };
  ushort* sT0   = (ushort*)alloc((size_t)7 * 512 * 512 * 2);
  ushort* sT1   = (ushort*)alloc((size_t)7 * 256 * 512 * 2);
  ushort* sT2   = (ushort*)alloc((size_t)7 * 64 * 256 * 2);
  float*  bias0 = (float*)alloc(7 * 512 * 4);
  float*  bias1 = (float*)alloc(7 * 256 * 4);
  float*  bias2 = (float*)alloc(7 * 64 * 4);
  int*    bcnt  = (int*)alloc(NBLK * NSCENE * 4);
  int*    rank  = (int*)alloc(BATCH * 4);
  int*    idxp  = (int*)alloc(PADMAX * 4);
  int*    plan  = (int*)alloc(32 * 4);
  ushort* hc1   = (ushort*)alloc((size_t)PADMAX * 512 * 2);
  (void)ws_size; (void)n_in; (void)in_sizes; (void)out_size;

  prep_k<<<NB_W0 + NB_W1 + NB_W2 + NB_BIAS + NB_CNT, 256, 0, stream>>>(
      W0, gW0, W1, gW1, W2, gW2, b0, gb0, b1, gb1, b2, gb2, scene,
      sT0, sT1, sT2, bias0, bias1, bias2, bcnt, rank);
  idx_k<<<NBLK, 256, 0, stream>>>(scene, rank, bcnt, idxp, plan);

  gemm0_k<<<dim3(MT_MAX * 2, 4), 256, 0, stream>>>(x, idxp, sT0, bias0, plan, hc1);
  gemm12_k<<<dim3(MT_MAX * 2), 256, 0, stream>>>(hc1, sT1, sT2, bias1, bias2,
                                                 plan, idxp, out);
}